// Round 1
// baseline (393.252 us; speedup 1.0000x reference)
//
#include <hip/hip_runtime.h>
#include <hip/hip_bf16.h>

#define S_LEN 512
#define BSZ 64
#define HDIM 1024
#define H2 2048

typedef float f32x4 __attribute__((ext_vector_type(4)));
typedef short short8 __attribute__((ext_vector_type(8)));
typedef __bf16 bf16x8 __attribute__((ext_vector_type(8)));

__device__ __forceinline__ unsigned short f2bf(float x) {
    union { float f; unsigned u; } v; v.f = x;
    unsigned r = (v.u + 0x7FFFu + ((v.u >> 16) & 1u)) >> 16;  // RNE
    return (unsigned short)r;
}

// ---------------- K0: zero the logit accumulator (d_out) ----------------
__global__ __launch_bounds__(256) void k_zero(float* __restrict__ p) {
    p[blockIdx.x * 256 + threadIdx.x] = 0.f;
}

// ---------------- K1: e1[b,h] = hidden[b,:] . Wa[h,0:1024] + ba[h] (f32 exact) ----
__global__ __launch_bounds__(256) void k_e1(const float* __restrict__ hidden,
                                            const float* __restrict__ Wa,
                                            const float* __restrict__ ba,
                                            float* __restrict__ e1) {
    __shared__ __align__(16) float hsh[HDIM];
    int b = blockIdx.x >> 2;
    int h = ((blockIdx.x & 3) << 8) + threadIdx.x;
    for (int i = threadIdx.x; i < HDIM; i += 256) hsh[i] = hidden[b * HDIM + i];
    __syncthreads();
    const float* wr = Wa + (size_t)h * H2;  // first H columns = hidden part
    float acc = 0.f;
#pragma unroll 8
    for (int k = 0; k < HDIM; k += 4) {
        f32x4 w = *(const f32x4*)(wr + k);
        f32x4 hh = *(const f32x4*)(hsh + k);
        acc += w[0] * hh[0] + w[1] * hh[1] + w[2] * hh[2] + w[3] * hh[3];
    }
    e1[b * HDIM + h] = acc + ba[h];
}

// ---------------- K2: pack Wa2 (f32) -> bf16 tiles in staging order --------------
// wsB layout: tile (nt in 0..7, kt in 0..31), each tile 128x32 bf16 (8KB) stored so
// that a LINEAR global_load_lds produces LDS[row][slot] = Wa2[n0+row][k0+(slot^swz(row))*8..]
// swz(row) = (row>>1)&3  (gives 2-way (free) LDS bank access on ds_read_b128)
__global__ __launch_bounds__(256) void k_packB(const float* __restrict__ Wa,
                                               unsigned short* __restrict__ wsB) {
    int ci = blockIdx.x * 256 + threadIdx.x;      // 16B chunk id, 0..131071
    int tile = ci >> 9;                           // 512 chunks per tile
    int wi = ci & 511;
    int row = wi >> 2;
    int slot = wi & 3;
    int nt = tile >> 5, kt = tile & 31;
    int n = nt * 128 + row;
    int kk = kt * 32 + ((slot ^ ((row >> 1) & 3)) << 3);
    const float* src = Wa + (size_t)n * H2 + HDIM + kk;  // second-H (encoder) part
    f32x4 a = *(const f32x4*)src;
    f32x4 b = *(const f32x4*)(src + 4);
    short8 o;
    o[0] = (short)f2bf(a[0]); o[1] = (short)f2bf(a[1]);
    o[2] = (short)f2bf(a[2]); o[3] = (short)f2bf(a[3]);
    o[4] = (short)f2bf(b[0]); o[5] = (short)f2bf(b[1]);
    o[6] = (short)f2bf(b[2]); o[7] = (short)f2bf(b[3]);
    *(short8*)(wsB + (size_t)ci * 8) = o;
}

// ---------------- K3: fused GEMM (enc_bf16 @ Wa2^T) + relu + Ws-dot -> atomic logits
// 128x128 tile, K-step 32, 4 waves (2x2 of 64x64), mfma_f32_16x16x32_bf16.
__global__ __launch_bounds__(256) void k_main(const float* __restrict__ enc,
                                              const unsigned short* __restrict__ wsB,
                                              const float* __restrict__ e1,
                                              const float* __restrict__ Ws,
                                              float* __restrict__ logits) {
    __shared__ __align__(16) unsigned short As[4096];  // [128][32] bf16, swizzled slots
    __shared__ __align__(16) unsigned short Bs[4096];

    int i = blockIdx.x;
    // XCD-aware mapping: blocks with the same mt (sharing the A-tile) land on one XCD.
    int mt = ((i >> 6) << 3) | (i & 7);
    int nt = (i >> 3) & 7;
    int r0 = mt * 128;
    int n0 = nt * 128;

    int tid = threadIdx.x;
    int lane = tid & 63, wid = tid >> 6;
    int wr = wid >> 1, wc = wid & 1;
    int c = lane & 15, g = lane >> 4;

    f32x4 acc[4][4] = {};

    for (int k0 = 0; k0 < HDIM; k0 += 32) {
        // --- stage B: async global->LDS, 2 x (256 lanes x 16B) = 8KB
        const unsigned short* bsrc = wsB + ((size_t)(nt * 32 + (k0 >> 5)) << 12);
        char* lbase = (char*)Bs + wid * 1024;  // wave-uniform base (+lane*16 implicit)
        __builtin_amdgcn_global_load_lds(
            (const __attribute__((address_space(1))) void*)(bsrc + (size_t)tid * 8),
            (__attribute__((address_space(3))) void*)lbase, 16, 0, 0);
        __builtin_amdgcn_global_load_lds(
            (const __attribute__((address_space(1))) void*)(bsrc + (size_t)(tid + 256) * 8),
            (__attribute__((address_space(3))) void*)(lbase + 4096), 16, 0, 0);

        // --- stage A: f32 load -> bf16 convert -> swizzled ds_write_b128
#pragma unroll
        for (int it = 0; it < 2; ++it) {
            int row = (it << 6) + (tid >> 2);   // 0..127
            int slot = tid & 3;
            int kk = k0 + ((slot ^ ((row >> 1) & 3)) << 3);
            const float* src = enc + (size_t)(r0 + row) * HDIM + kk;
            f32x4 a = *(const f32x4*)src;
            f32x4 b = *(const f32x4*)(src + 4);
            short8 o;
            o[0] = (short)f2bf(a[0]); o[1] = (short)f2bf(a[1]);
            o[2] = (short)f2bf(a[2]); o[3] = (short)f2bf(a[3]);
            o[4] = (short)f2bf(b[0]); o[5] = (short)f2bf(b[1]);
            o[6] = (short)f2bf(b[2]); o[7] = (short)f2bf(b[3]);
            *(short8*)((char*)As + row * 64 + slot * 16) = o;
        }
        __syncthreads();

        // --- fragments + MFMA
        bf16x8 af[4], bfr[4];
#pragma unroll
        for (int m = 0; m < 4; ++m) {
            int row = wr * 64 + m * 16 + c;
            int slot = g ^ ((row >> 1) & 3);
            af[m] = *(const bf16x8*)((const char*)As + row * 64 + slot * 16);
        }
#pragma unroll
        for (int n = 0; n < 4; ++n) {
            int rowb = wc * 64 + n * 16 + c;
            int slot = g ^ ((rowb >> 1) & 3);
            bfr[n] = *(const bf16x8*)((const char*)Bs + rowb * 64 + slot * 16);
        }
#pragma unroll
        for (int m = 0; m < 4; ++m)
#pragma unroll
            for (int n = 0; n < 4; ++n)
                acc[m][n] = __builtin_amdgcn_mfma_f32_16x16x32_bf16(af[m], bfr[n], acc[m][n], 0, 0, 0);
        __syncthreads();
    }

    // --- epilogue: v = relu(acc + e1[b,h]); partial[r] += v*Ws[h]; atomicAdd
    float wsv[4];
#pragma unroll
    for (int n = 0; n < 4; ++n) wsv[n] = Ws[n0 + wc * 64 + n * 16 + c];

#pragma unroll
    for (int m = 0; m < 4; ++m) {
#pragma unroll
        for (int j = 0; j < 4; ++j) {
            int rl = wr * 64 + m * 16 + g * 4 + j;
            int r = r0 + rl;
            int b = r & 63, sidx = r >> 6;
            const float* e1b = e1 + b * HDIM + n0 + wc * 64;
            float p = 0.f;
#pragma unroll
            for (int n = 0; n < 4; ++n) {
                float v = acc[m][n][j] + e1b[n * 16 + c];
                v = fmaxf(v, 0.f);
                p += v * wsv[n];
            }
            p += __shfl_xor(p, 1);
            p += __shfl_xor(p, 2);
            p += __shfl_xor(p, 4);
            p += __shfl_xor(p, 8);
            if (c == 0) atomicAdd(&logits[b * S_LEN + sidx], p);
        }
    }
}

// ---------------- K4: logits -> softmax probs, in place on d_out ----------------
__global__ __launch_bounds__(512) void k_softmax(float* __restrict__ out,
                                                 const float* __restrict__ pe,
                                                 const int* __restrict__ mask,
                                                 float scale) {
    __shared__ float red[8];
    int b = blockIdx.x, s = threadIdx.x;
    int idx = (b << 9) + s;
    float acc = out[idx];
    float logit = (mask[idx] != 0) ? -1e12f : (scale * acc + pe[idx]);
    float m = logit;
#pragma unroll
    for (int o = 32; o >= 1; o >>= 1) m = fmaxf(m, __shfl_xor(m, o));
    if ((s & 63) == 0) red[s >> 6] = m;
    __syncthreads();
    float m2 = red[0];
#pragma unroll
    for (int i2 = 1; i2 < 8; ++i2) m2 = fmaxf(m2, red[i2]);
    float e = expf(logit - m2);
    float t = e;
#pragma unroll
    for (int o = 32; o >= 1; o >>= 1) t += __shfl_xor(t, o);
    __syncthreads();
    if ((s & 63) == 0) red[s >> 6] = t;
    __syncthreads();
    float tot = 0.f;
#pragma unroll
    for (int i2 = 0; i2 < 8; ++i2) tot += red[i2];
    out[idx] = e / tot;
}

extern "C" void kernel_launch(void* const* d_in, const int* in_sizes, int n_in,
                              void* d_out, int out_size, void* d_ws, size_t ws_size,
                              hipStream_t stream) {
    const float* hidden = (const float*)d_in[0];
    const float* enc    = (const float*)d_in[1];
    const float* pe     = (const float*)d_in[2];
    const int*   mask   = (const int*)d_in[3];   // jax bool -> int32 per harness convention
    const float* Wa     = (const float*)d_in[4];
    const float* ba     = (const float*)d_in[5];
    const float* Ws     = (const float*)d_in[6];
    float* out = (float*)d_out;

    float* e1 = (float*)d_ws;                                  // 64*1024 f32 = 256KB
    unsigned short* wsB = (unsigned short*)((char*)d_ws + 262144);  // 1M bf16 = 2MB

    const float scale = 0.19494764453248462f;  // log(512)/sqrt(1024)

    k_zero<<<128, 256, 0, stream>>>(out);
    k_e1<<<256, 256, 0, stream>>>(hidden, Wa, ba, e1);
    k_packB<<<512, 256, 0, stream>>>(Wa, wsB);
    k_main<<<2048, 256, 0, stream>>>(enc, wsB, e1, Ws, out);
    k_softmax<<<64, 512, 0, stream>>>(out, pe, mask, scale);
}

// Round 2
// 370.523 us; speedup vs baseline: 1.0613x; 1.0613x over previous
//
#include <hip/hip_runtime.h>
#include <hip/hip_bf16.h>

#define S_LEN 512
#define BSZ 64
#define HDIM 1024
#define H2 2048

typedef float f32x4 __attribute__((ext_vector_type(4)));
typedef short short8 __attribute__((ext_vector_type(8)));
typedef __bf16 bf16x8 __attribute__((ext_vector_type(8)));

// ---------------- K0: zero the logit accumulator (d_out) ----------------
__global__ __launch_bounds__(256) void k_zero(float* __restrict__ p) {
    p[blockIdx.x * 256 + threadIdx.x] = 0.f;
}

// ---------------- K1: e1[b,h] = hidden[b,:] . Wa[h,0:1024] + ba[h]  (f32 exact)
// One wave per output; lanes read along K -> coalesced 1KB segments.
__global__ __launch_bounds__(256) void k_e1(const float* __restrict__ hidden,
                                            const float* __restrict__ Wa,
                                            const float* __restrict__ ba,
                                            float* __restrict__ e1) {
    int wg = blockIdx.x * 4 + (threadIdx.x >> 6);  // 0..65535 = b*1024 + h
    int lane = threadIdx.x & 63;
    int b = wg >> 10, h = wg & 1023;
    const float* hr = hidden + b * HDIM;
    const float* wr = Wa + (size_t)h * H2;  // first H columns = hidden part
    float acc = 0.f;
#pragma unroll
    for (int j = 0; j < 4; ++j) {
        f32x4 hv = *(const f32x4*)(hr + j * 256 + lane * 4);
        f32x4 wv = *(const f32x4*)(wr + j * 256 + lane * 4);
        acc += hv[0] * wv[0] + hv[1] * wv[1] + hv[2] * wv[2] + hv[3] * wv[3];
    }
#pragma unroll
    for (int o = 32; o >= 1; o >>= 1) acc += __shfl_xor(acc, o);
    if (lane == 0) e1[wg] = acc + ba[h];
}

// ---------------- K2: pack Wa2 (f32) -> bf16 tiles in global_load_lds order ----
// tile (nt,kt): 128x32 bf16, chunk wi = row*4+slot holds cols (slot^swz(row))*8..
// swz(row) = (row>>1)&3
__global__ __launch_bounds__(256) void k_packB(const float* __restrict__ Wa,
                                               unsigned short* __restrict__ wsB) {
    int ci = blockIdx.x * 256 + threadIdx.x;      // 16B chunk id, 0..131071
    int tile = ci >> 9;
    int wi = ci & 511;
    int row = wi >> 2;
    int slot = wi & 3;
    int nt = tile >> 5, kt = tile & 31;
    int n = nt * 128 + row;
    int kk = kt * 32 + ((slot ^ ((row >> 1) & 3)) << 3);
    const float* src = Wa + (size_t)n * H2 + HDIM + kk;  // encoder half
    f32x4 a = *(const f32x4*)src;
    f32x4 b = *(const f32x4*)(src + 4);
    bf16x8 o;
    o[0] = (__bf16)a[0]; o[1] = (__bf16)a[1]; o[2] = (__bf16)a[2]; o[3] = (__bf16)a[3];
    o[4] = (__bf16)b[0]; o[5] = (__bf16)b[1]; o[6] = (__bf16)b[2]; o[7] = (__bf16)b[3];
    *(bf16x8*)(wsB + (size_t)ci * 8) = o;
}

// ---------------- K2b: pack enc (f32) -> bf16 tiles, same layout, per (mt,kt) ----
// Linear coalesced reads; writes land as 64B segments inside tiles.
__global__ __launch_bounds__(256) void k_packA(const float* __restrict__ enc,
                                               unsigned short* __restrict__ wsA) {
    int ci = blockIdx.x * 256 + threadIdx.x;      // 0..4194303 source 32B chunks
    const float* src = enc + (size_t)ci * 8;
    f32x4 a = *(const f32x4*)src;
    f32x4 b = *(const f32x4*)(src + 4);
    int row_g = ci >> 7;          // global row 0..32767
    int cchunk = ci & 127;        // 8-float chunk within row
    int kt = cchunk >> 2, slot_src = cchunk & 3;
    int mt = row_g >> 7, row = row_g & 127;
    int slot = slot_src ^ ((row >> 1) & 3);
    size_t dst = ((((size_t)(mt * 32 + kt)) << 9) + (row << 2) + slot) << 3;  // elems
    bf16x8 o;
    o[0] = (__bf16)a[0]; o[1] = (__bf16)a[1]; o[2] = (__bf16)a[2]; o[3] = (__bf16)a[3];
    o[4] = (__bf16)b[0]; o[5] = (__bf16)b[1]; o[6] = (__bf16)b[2]; o[7] = (__bf16)b[3];
    *(bf16x8*)(wsA + dst) = o;
}

// ---------------- K3: fused GEMM (enc_bf16 @ Wa2^T) + relu + Ws-dot -> atomic logits
// m97 structure: 128x128 tile, BK=32, both operands via global_load_lds width 16.
__global__ __launch_bounds__(256) void k_main_pre(const unsigned short* __restrict__ wsA,
                                                  const unsigned short* __restrict__ wsB,
                                                  const float* __restrict__ e1,
                                                  const float* __restrict__ Ws,
                                                  float* __restrict__ logits) {
    __shared__ __align__(16) unsigned short As[4096];  // [128][32] bf16, swizzled slots
    __shared__ __align__(16) unsigned short Bs[4096];

    int i = blockIdx.x;
    // XCD-aware mapping: the 8 n-blocks sharing an A-tile land on one XCD.
    int mt = ((i >> 6) << 3) | (i & 7);
    int nt = (i >> 3) & 7;
    int r0 = mt * 128;
    int n0 = nt * 128;

    int tid = threadIdx.x;
    int lane = tid & 63, wid = tid >> 6;
    int wr = wid >> 1, wc = wid & 1;
    int c = lane & 15, g = lane >> 4;

    f32x4 acc[4][4] = {};

    for (int k0 = 0; k0 < HDIM; k0 += 32) {
        int kt = k0 >> 5;
        const unsigned short* asrc = wsA + ((size_t)(mt * 32 + kt) << 12);
        const unsigned short* bsrc = wsB + ((size_t)(nt * 32 + kt) << 12);
        char* la = (char*)As + wid * 1024;
        char* lb = (char*)Bs + wid * 1024;
        __builtin_amdgcn_global_load_lds(
            (const __attribute__((address_space(1))) void*)(asrc + (size_t)tid * 8),
            (__attribute__((address_space(3))) void*)la, 16, 0, 0);
        __builtin_amdgcn_global_load_lds(
            (const __attribute__((address_space(1))) void*)(asrc + (size_t)(tid + 256) * 8),
            (__attribute__((address_space(3))) void*)(la + 4096), 16, 0, 0);
        __builtin_amdgcn_global_load_lds(
            (const __attribute__((address_space(1))) void*)(bsrc + (size_t)tid * 8),
            (__attribute__((address_space(3))) void*)lb, 16, 0, 0);
        __builtin_amdgcn_global_load_lds(
            (const __attribute__((address_space(1))) void*)(bsrc + (size_t)(tid + 256) * 8),
            (__attribute__((address_space(3))) void*)(lb + 4096), 16, 0, 0);
        __syncthreads();

        bf16x8 af[4], bfr[4];
#pragma unroll
        for (int m = 0; m < 4; ++m) {
            int row = wr * 64 + m * 16 + c;
            int slot = g ^ ((row >> 1) & 3);
            af[m] = *(const bf16x8*)((const char*)As + row * 64 + slot * 16);
        }
#pragma unroll
        for (int n = 0; n < 4; ++n) {
            int rowb = wc * 64 + n * 16 + c;
            int slot = g ^ ((rowb >> 1) & 3);
            bfr[n] = *(const bf16x8*)((const char*)Bs + rowb * 64 + slot * 16);
        }
#pragma unroll
        for (int m = 0; m < 4; ++m)
#pragma unroll
            for (int n = 0; n < 4; ++n)
                acc[m][n] = __builtin_amdgcn_mfma_f32_16x16x32_bf16(af[m], bfr[n], acc[m][n], 0, 0, 0);
        __syncthreads();
    }

    float wsv[4];
#pragma unroll
    for (int n = 0; n < 4; ++n) wsv[n] = Ws[n0 + wc * 64 + n * 16 + c];

#pragma unroll
    for (int m = 0; m < 4; ++m) {
#pragma unroll
        for (int j = 0; j < 4; ++j) {
            int rl = wr * 64 + m * 16 + g * 4 + j;
            int r = r0 + rl;
            int b = r & 63, sidx = r >> 6;
            const float* e1b = e1 + b * HDIM + n0 + wc * 64;
            float p = 0.f;
#pragma unroll
            for (int n = 0; n < 4; ++n) {
                float v = acc[m][n][j] + e1b[n * 16 + c];
                v = fmaxf(v, 0.f);
                p += v * wsv[n];
            }
            p += __shfl_xor(p, 1);
            p += __shfl_xor(p, 2);
            p += __shfl_xor(p, 4);
            p += __shfl_xor(p, 8);
            if (c == 0) atomicAdd(&logits[b * S_LEN + sidx], p);
        }
    }
}

// ---------------- Fallback (small ws): in-loop cast-convert A (compiler cvt_pk) ----
__global__ __launch_bounds__(256) void k_main_cvt(const float* __restrict__ enc,
                                                  const unsigned short* __restrict__ wsB,
                                                  const float* __restrict__ e1,
                                                  const float* __restrict__ Ws,
                                                  float* __restrict__ logits) {
    __shared__ __align__(16) unsigned short As[4096];
    __shared__ __align__(16) unsigned short Bs[4096];

    int i = blockIdx.x;
    int mt = ((i >> 6) << 3) | (i & 7);
    int nt = (i >> 3) & 7;
    int r0 = mt * 128;
    int n0 = nt * 128;

    int tid = threadIdx.x;
    int lane = tid & 63, wid = tid >> 6;
    int wr = wid >> 1, wc = wid & 1;
    int c = lane & 15, g = lane >> 4;

    f32x4 acc[4][4] = {};

    for (int k0 = 0; k0 < HDIM; k0 += 32) {
        const unsigned short* bsrc = wsB + ((size_t)(nt * 32 + (k0 >> 5)) << 12);
        char* lb = (char*)Bs + wid * 1024;
        __builtin_amdgcn_global_load_lds(
            (const __attribute__((address_space(1))) void*)(bsrc + (size_t)tid * 8),
            (__attribute__((address_space(3))) void*)lb, 16, 0, 0);
        __builtin_amdgcn_global_load_lds(
            (const __attribute__((address_space(1))) void*)(bsrc + (size_t)(tid + 256) * 8),
            (__attribute__((address_space(3))) void*)(lb + 4096), 16, 0, 0);

#pragma unroll
        for (int it = 0; it < 2; ++it) {
            int row = (it << 6) + (tid >> 2);
            int slot = tid & 3;
            int kk = k0 + ((slot ^ ((row >> 1) & 3)) << 3);
            const float* src = enc + (size_t)(r0 + row) * HDIM + kk;
            f32x4 a = *(const f32x4*)src;
            f32x4 b = *(const f32x4*)(src + 4);
            bf16x8 o;
            o[0] = (__bf16)a[0]; o[1] = (__bf16)a[1]; o[2] = (__bf16)a[2]; o[3] = (__bf16)a[3];
            o[4] = (__bf16)b[0]; o[5] = (__bf16)b[1]; o[6] = (__bf16)b[2]; o[7] = (__bf16)b[3];
            *(bf16x8*)((char*)As + row * 64 + slot * 16) = o;
        }
        __syncthreads();

        bf16x8 af[4], bfr[4];
#pragma unroll
        for (int m = 0; m < 4; ++m) {
            int row = wr * 64 + m * 16 + c;
            int slot = g ^ ((row >> 1) & 3);
            af[m] = *(const bf16x8*)((const char*)As + row * 64 + slot * 16);
        }
#pragma unroll
        for (int n = 0; n < 4; ++n) {
            int rowb = wc * 64 + n * 16 + c;
            int slot = g ^ ((rowb >> 1) & 3);
            bfr[n] = *(const bf16x8*)((const char*)Bs + rowb * 64 + slot * 16);
        }
#pragma unroll
        for (int m = 0; m < 4; ++m)
#pragma unroll
            for (int n = 0; n < 4; ++n)
                acc[m][n] = __builtin_amdgcn_mfma_f32_16x16x32_bf16(af[m], bfr[n], acc[m][n], 0, 0, 0);
        __syncthreads();
    }

    float wsv[4];
#pragma unroll
    for (int n = 0; n < 4; ++n) wsv[n] = Ws[n0 + wc * 64 + n * 16 + c];

#pragma unroll
    for (int m = 0; m < 4; ++m) {
#pragma unroll
        for (int j = 0; j < 4; ++j) {
            int rl = wr * 64 + m * 16 + g * 4 + j;
            int r = r0 + rl;
            int b = r & 63, sidx = r >> 6;
            const float* e1b = e1 + b * HDIM + n0 + wc * 64;
            float p = 0.f;
#pragma unroll
            for (int n = 0; n < 4; ++n) {
                float v = acc[m][n][j] + e1b[n * 16 + c];
                v = fmaxf(v, 0.f);
                p += v * wsv[n];
            }
            p += __shfl_xor(p, 1);
            p += __shfl_xor(p, 2);
            p += __shfl_xor(p, 4);
            p += __shfl_xor(p, 8);
            if (c == 0) atomicAdd(&logits[b * S_LEN + sidx], p);
        }
    }
}

// ---------------- K4: logits -> softmax probs, in place on d_out ----------------
__global__ __launch_bounds__(512) void k_softmax(float* __restrict__ out,
                                                 const float* __restrict__ pe,
                                                 const int* __restrict__ mask,
                                                 float scale) {
    __shared__ float red[8];
    int b = blockIdx.x, s = threadIdx.x;
    int idx = (b << 9) + s;
    float acc = out[idx];
    float logit = (mask[idx] != 0) ? -1e12f : (scale * acc + pe[idx]);
    float m = logit;
#pragma unroll
    for (int o = 32; o >= 1; o >>= 1) m = fmaxf(m, __shfl_xor(m, o));
    if ((s & 63) == 0) red[s >> 6] = m;
    __syncthreads();
    float m2 = red[0];
#pragma unroll
    for (int i2 = 1; i2 < 8; ++i2) m2 = fmaxf(m2, red[i2]);
    float e = expf(logit - m2);
    float t = e;
#pragma unroll
    for (int o = 32; o >= 1; o >>= 1) t += __shfl_xor(t, o);
    __syncthreads();
    if ((s & 63) == 0) red[s >> 6] = t;
    __syncthreads();
    float tot = 0.f;
#pragma unroll
    for (int i2 = 0; i2 < 8; ++i2) tot += red[i2];
    out[idx] = e / tot;
}

extern "C" void kernel_launch(void* const* d_in, const int* in_sizes, int n_in,
                              void* d_out, int out_size, void* d_ws, size_t ws_size,
                              hipStream_t stream) {
    const float* hidden = (const float*)d_in[0];
    const float* enc    = (const float*)d_in[1];
    const float* pe     = (const float*)d_in[2];
    const int*   mask   = (const int*)d_in[3];
    const float* Wa     = (const float*)d_in[4];
    const float* ba     = (const float*)d_in[5];
    const float* Ws     = (const float*)d_in[6];
    float* out = (float*)d_out;

    float* e1 = (float*)d_ws;                                       // 256 KB
    unsigned short* wsB = (unsigned short*)((char*)d_ws + 262144);  // 2 MB
    unsigned short* wsA = (unsigned short*)((char*)d_ws + 262144 + 2097152);  // 64 MB

    const size_t need = 262144 + 2097152 + (size_t)32768 * 1024 * 2;
    const bool pre = ws_size >= need;

    const float scale = 0.19494764453248462f;  // log(512)/sqrt(1024)

    k_zero<<<128, 256, 0, stream>>>(out);
    k_e1<<<16384, 256, 0, stream>>>(hidden, Wa, ba, e1);
    k_packB<<<512, 256, 0, stream>>>(Wa, wsB);
    if (pre) {
        k_packA<<<16384, 256, 0, stream>>>(enc, wsA);
        k_main_pre<<<2048, 256, 0, stream>>>(wsA, wsB, e1, Ws, out);
    } else {
        k_main_cvt<<<2048, 256, 0, stream>>>(enc, wsB, e1, Ws, out);
    }
    k_softmax<<<64, 512, 0, stream>>>(out, pe, mask, scale);
}